// Round 8
// baseline (625.772 us; speedup 1.0000x reference)
//
#include <hip/hip_runtime.h>
#include <hip/hip_bf16.h>
#include <stdint.h>
#include <stddef.h>

#define NN 50000
#define NE 800000

typedef __attribute__((ext_vector_type(8))) __bf16 bf16x8;
typedef __attribute__((ext_vector_type(4))) __bf16 bf16x4;
typedef __attribute__((ext_vector_type(2))) __bf16 bf16x2;
typedef __attribute__((ext_vector_type(4))) float  f32x4;

static __device__ __forceinline__ f32x4 ld4(const float* p)  { return *(const f32x4*)p; }
static __device__ __forceinline__ f32x4 ld4(const __bf16* p) {
    bf16x4 v = *(const bf16x4*)p;
    return (f32x4){(float)v[0], (float)v[1], (float)v[2], (float)v[3]};
}
static __device__ __forceinline__ f32x4 ld4_nt(const float* p) {
    return __builtin_nontemporal_load((const f32x4*)p);
}
static __device__ __forceinline__ f32x4 relu4(f32x4 a) {
    return (f32x4){fmaxf(a[0], 0.f), fmaxf(a[1], 0.f), fmaxf(a[2], 0.f), fmaxf(a[3], 0.f)};
}
static __device__ __forceinline__ bf16x4 tobf4(f32x4 a) {
    bf16x4 o; o[0] = (__bf16)a[0]; o[1] = (__bf16)a[1]; o[2] = (__bf16)a[2]; o[3] = (__bf16)a[3];
    return o;
}

// ---------------- prep: zero cnt/done + weights->bf16 + nfeats->bf16 ----------------
__global__ __launch_bounds__(256) void k_prep(int* __restrict__ cnt, int* __restrict__ done,
                                              const float* __restrict__ a, __bf16* __restrict__ oa,
                                              const float* __restrict__ b, __bf16* __restrict__ ob,
                                              const float* __restrict__ c, __bf16* __restrict__ oc,
                                              const float* __restrict__ d, __bf16* __restrict__ od,
                                              const float* __restrict__ nf, __bf16* __restrict__ nfbf) {
    int i = blockIdx.x * 256 + threadIdx.x;       // grid 2048 -> 524288 threads
    if (i == 0) *done = 0;
    if (i < NN) cnt[i] = 0;
    if (i < 128 * 384) { oa[i] = (__bf16)a[i]; oc[i] = (__bf16)c[i]; }
    if (i < 128 * 256) { ob[i] = (__bf16)b[i]; od[i] = (__bf16)d[i]; }
    int stride = gridDim.x * 256;
    for (int j = i; j < NN * 128 / 8; j += stride) {
        f32x4 x = __builtin_nontemporal_load((const f32x4*)(nf + (size_t)j * 8));
        f32x4 y = __builtin_nontemporal_load((const f32x4*)(nf + (size_t)j * 8 + 4));
        bf16x8 o;
        o[0] = (__bf16)x[0]; o[1] = (__bf16)x[1]; o[2] = (__bf16)x[2]; o[3] = (__bf16)x[3];
        o[4] = (__bf16)y[0]; o[5] = (__bf16)y[1]; o[6] = (__bf16)y[2]; o[7] = (__bf16)y[3];
        *(bf16x8*)(nfbf + (size_t)j * 8) = o;
    }
}

// ---------------- CSR build ----------------
__global__ __launch_bounds__(256) void k_count(const int* __restrict__ v, int* __restrict__ cnt) {
    int i = blockIdx.x * 256 + threadIdx.x;
    int stride = gridDim.x * 256;
    for (; i < NE; i += stride) atomicAdd(&cnt[v[i]], 1);
}

// stage A: per-1024-chunk sums; LAST block also scans the 49 partials (saves a launch)
__global__ __launch_bounds__(1024) void k_scanA(const int* __restrict__ cnt,
                                                int* __restrict__ bsum,
                                                int* __restrict__ boff,
                                                int* __restrict__ off,
                                                int* __restrict__ done) {
    __shared__ int sh[1024];
    int b = blockIdx.x;                 // 0..48
    int t = threadIdx.x;
    int idx = b * 1024 + t;
    int val = (idx < NN) ? cnt[idx] : 0;
    sh[t] = val;
    __syncthreads();
    for (int d = 512; d > 0; d >>= 1) {
        if (t < d) sh[t] += sh[t + d];
        __syncthreads();
    }
    __shared__ int amLast;
    if (t == 0) {
        bsum[b] = sh[0];
        __threadfence();
        amLast = (atomicAdd(done, 1) == 48);
    }
    __syncthreads();
    if (amLast && t < 64) {
        __threadfence();
        int lane = t;
        int s = (lane < 49) ? bsum[lane] : 0;
        int incl = s;
        for (int d = 1; d < 64; d <<= 1) {
            int x = __shfl_up(incl, d);
            if (lane >= d) incl += x;
        }
        if (lane < 49) boff[lane] = incl - s;
        if (lane == 48) off[NN] = incl;
    }
}

__global__ __launch_bounds__(1024) void k_scanC(const int* __restrict__ cnt,
                                                const int* __restrict__ boff,
                                                int* __restrict__ off,
                                                int* __restrict__ cur) {
    __shared__ int sh[1024];
    int b = blockIdx.x;
    int t = threadIdx.x;
    int idx = b * 1024 + t;
    int val = (idx < NN) ? cnt[idx] : 0;
    sh[t] = val;
    __syncthreads();
    for (int d = 1; d < 1024; d <<= 1) {
        int x = (t >= d) ? sh[t - d] : 0;
        __syncthreads();
        sh[t] += x;
        __syncthreads();
    }
    int excl = sh[t] - val + boff[b];
    if (idx < NN) { off[idx] = excl; cur[idx] = excl; }
}

__global__ __launch_bounds__(256) void k_fill(const int* __restrict__ u,
                                              const int* __restrict__ v,
                                              int* __restrict__ cur,
                                              int2* __restrict__ se) {
    int i = blockIdx.x * 256 + threadIdx.x;
    int stride = gridDim.x * 256;
    for (; i < NE; i += stride) {
        int uu = __builtin_nontemporal_load(u + i);
        int vv = __builtin_nontemporal_load(v + i);
        int pos = atomicAdd(&cur[vv], 1);
        se[pos] = make_int2(uu, i);
    }
}

// ---------------- aggregation bodies: 16 outstanding gathers, then 4, then 1 ----------------
// X[n][256] = [mean_src | mean_edge]; self features NOT copied (MLP reads them directly).

__global__ __launch_bounds__(256) void k_agg1(const __bf16* __restrict__ nfbf,
                                              const float* __restrict__ ef,
                                              const int2* __restrict__ se,
                                              const int* __restrict__ off,
                                              __bf16* __restrict__ X) {
    const int wid  = threadIdx.x >> 6;
    const int lane = threadIdx.x & 63;
    const int n = blockIdx.x * 4 + wid;
    const int p0 = __builtin_amdgcn_readfirstlane(off[n]);
    const int p1 = __builtin_amdgcn_readfirstlane(off[n + 1]);
    const bool isE = lane >= 32;
    const int l = lane & 31;

    f32x4 acc = {0.f, 0.f, 0.f, 0.f};
    int p = p0;
    for (; p + 16 <= p1; p += 16) {
        int2 g[16];
#pragma unroll
        for (int j = 0; j < 16; ++j) g[j] = se[p + j];
        f32x4 t[16];
        if (isE) {
#pragma unroll
            for (int j = 0; j < 16; ++j) t[j] = ld4_nt(ef + (size_t)g[j].y * 128 + l * 4);
        } else {
#pragma unroll
            for (int j = 0; j < 16; ++j) t[j] = ld4(nfbf + (size_t)g[j].x * 128 + l * 4);
        }
#pragma unroll
        for (int j = 0; j < 16; ++j) acc += t[j];
    }
    for (; p + 4 <= p1; p += 4) {
        int2 g[4];
#pragma unroll
        for (int j = 0; j < 4; ++j) g[j] = se[p + j];
        f32x4 t[4];
#pragma unroll
        for (int j = 0; j < 4; ++j)
            t[j] = isE ? ld4_nt(ef + (size_t)g[j].y * 128 + l * 4)
                       : ld4(nfbf + (size_t)g[j].x * 128 + l * 4);
#pragma unroll
        for (int j = 0; j < 4; ++j) acc += t[j];
    }
    for (; p < p1; ++p) {
        int2 g = se[p];
        acc += isE ? ld4_nt(ef + (size_t)g.y * 128 + l * 4)
                   : ld4(nfbf + (size_t)g.x * 128 + l * 4);
    }

    float inv = (p1 > p0) ? 1.f / (float)(p1 - p0) : 0.f;
    f32x4 m = {acc[0] * inv, acc[1] * inv, acc[2] * inv, acc[3] * inv};
    *(bf16x4*)(X + (size_t)n * 256 + (isE ? 128 : 0) + l * 4) = tobf4(m);
}

// HP1[n][256] = [h1[n] | P1[n]]; Q1 pre-biased.
// X2[n][256] = [mean h1[u], mean relu(P1[u] + Q1[n])]
__global__ __launch_bounds__(256) void k_agg2(const __bf16* __restrict__ HP1,
                                              const __bf16* __restrict__ Q1,
                                              const int2* __restrict__ se,
                                              const int* __restrict__ off,
                                              __bf16* __restrict__ X) {
    const int wid  = threadIdx.x >> 6;
    const int lane = threadIdx.x & 63;
    const int n = blockIdx.x * 4 + wid;
    const int p0 = __builtin_amdgcn_readfirstlane(off[n]);
    const int p1 = __builtin_amdgcn_readfirstlane(off[n + 1]);
    const bool isE = lane >= 32;                 // lanes 32-63 own the P-half of the row
    const int l = lane & 31;

    f32x4 qb = ld4(Q1 + (size_t)n * 128 + l * 4);   // bias already folded

    f32x4 acc = {0.f, 0.f, 0.f, 0.f};
    int p = p0;
    for (; p + 16 <= p1; p += 16) {
        int g[16];
#pragma unroll
        for (int j = 0; j < 16; ++j) g[j] = se[p + j].x;
        f32x4 t[16];
#pragma unroll
        for (int j = 0; j < 16; ++j) t[j] = ld4(HP1 + (size_t)g[j] * 256 + lane * 4);
#pragma unroll
        for (int j = 0; j < 16; ++j) acc += isE ? relu4(t[j] + qb) : t[j];
    }
    for (; p + 4 <= p1; p += 4) {
        int g[4];
#pragma unroll
        for (int j = 0; j < 4; ++j) g[j] = se[p + j].x;
        f32x4 t[4];
#pragma unroll
        for (int j = 0; j < 4; ++j) t[j] = ld4(HP1 + (size_t)g[j] * 256 + lane * 4);
#pragma unroll
        for (int j = 0; j < 4; ++j) acc += isE ? relu4(t[j] + qb) : t[j];
    }
    for (; p < p1; ++p) {
        int g = se[p].x;
        f32x4 t = ld4(HP1 + (size_t)g * 256 + lane * 4);
        acc += isE ? relu4(t + qb) : t;
    }

    float inv = (p1 > p0) ? 1.f / (float)(p1 - p0) : 0.f;
    f32x4 m = {acc[0] * inv, acc[1] * inv, acc[2] * inv, acc[3] * inv};
    *(bf16x4*)(X + (size_t)n * 256 + (isE ? 128 : 0) + l * 4) = tobf4(m);
}

// ---------------- fused node MLP + P/Q projection ----------------
// K-split GEMM: cols 0-127 of Wa apply to self rows (read from S, stride SS);
// cols 128-383 apply to the 256-wide mean buffer X.
// MODE 0: S=nfbf (SS=128); h,P -> HP1; Q+be -> Q1
// MODE 1: S=HP1 h-half (SS=256); h -> Hf f32 nt; P -> P2, Q+be -> Q2
template <int MODE>
__global__ __launch_bounds__(256) void k_mlp_pq(const __bf16* __restrict__ X,
                                                const __bf16* __restrict__ S,
                                                const __bf16* __restrict__ Wa,
                                                const float* __restrict__ ba,
                                                const __bf16* __restrict__ We,
                                                const float* __restrict__ be,
                                                __bf16* __restrict__ HP,
                                                __bf16* __restrict__ Q1,
                                                float* __restrict__ Hf,
                                                __bf16* __restrict__ P2,
                                                __bf16* __restrict__ Q2,
                                                int M) {
    const int K = 384;
    const int SS = (MODE == 0) ? 128 : 256;
    const int wave = threadIdx.x >> 6;
    const int lane = threadIdx.x & 63;
    const int m0 = blockIdx.x * 64 + wave * 16;
    const int lr = lane & 15;
    const int kg = lane >> 4;

    __shared__ __bf16 hlds[4 * 16 * 136];   // per-wave [16][136] bf16
    __bf16* my = hlds + wave * 16 * 136;

    f32x4 acc[8];
#pragma unroll
    for (int j = 0; j < 8; ++j) acc[j] = (f32x4){0.f, 0.f, 0.f, 0.f};

    int r0 = m0 + lr; if (r0 > M - 1) r0 = M - 1;
    const __bf16* ps0 = S + (size_t)r0 * SS + 8 * kg;   // self features
    const __bf16* px0 = X + (size_t)r0 * 256 + 8 * kg;  // mean features
    const __bf16* pwa = Wa + (size_t)lr * K + 8 * kg;

    // self part: Wa cols 0-127
#pragma unroll
    for (int k0 = 0; k0 < 128; k0 += 32) {
        bf16x8 x0 = *(const bf16x8*)(ps0 + k0);
#pragma unroll
        for (int j = 0; j < 8; ++j) {
            bf16x8 w = *(const bf16x8*)(pwa + (size_t)j * 16 * K + k0);
            acc[j] = __builtin_amdgcn_mfma_f32_16x16x32_bf16(w, x0, acc[j], 0, 0, 0);
        }
    }
    // mean part: Wa cols 128-383
#pragma unroll
    for (int k0 = 0; k0 < 256; k0 += 32) {
        bf16x8 x0 = *(const bf16x8*)(px0 + k0);
#pragma unroll
        for (int j = 0; j < 8; ++j) {
            bf16x8 w = *(const bf16x8*)(pwa + (size_t)j * 16 * K + 128 + k0);
            acc[j] = __builtin_amdgcn_mfma_f32_16x16x32_bf16(w, x0, acc[j], 0, 0, 0);
        }
    }

    // epilogue: store h + stage into LDS for the P/Q GEMM
    {
        int node = m0 + lr;
#pragma unroll
        for (int j = 0; j < 8; ++j) {
            int ch0 = j * 16 + kg * 4;
            f32x4 bb = *(const f32x4*)(ba + ch0);
            f32x4 val = relu4(acc[j] + bb);
            bf16x4 vb = tobf4(val);
            *(bf16x4*)(my + lr * 136 + ch0) = vb;
            if (node < M) {
                if (MODE == 0) *(bf16x4*)(HP + (size_t)node * 256 + ch0) = vb;
                else __builtin_nontemporal_store(val, (f32x4*)(Hf + (size_t)node * 128 + ch0));
            }
        }
    }
    __syncthreads();

    // second GEMM: P/Q from LDS h-tile (16 rows)
    f32x4 accP[8], accQ[8];
#pragma unroll
    for (int j = 0; j < 8; ++j) { accP[j] = (f32x4){0,0,0,0}; accQ[j] = (f32x4){0,0,0,0}; }

    const __bf16* pwe = We + (size_t)lr * 256 + 8 * kg;
#pragma unroll
    for (int k0 = 0; k0 < 128; k0 += 32) {
        bf16x8 h0 = *(const bf16x8*)(my + lr * 136 + k0 + 8 * kg);
#pragma unroll
        for (int j = 0; j < 8; ++j) {
            bf16x8 wp = *(const bf16x8*)(pwe + (size_t)j * 16 * 256 + k0);
            bf16x8 wq = *(const bf16x8*)(pwe + (size_t)j * 16 * 256 + 128 + k0);
            accP[j] = __builtin_amdgcn_mfma_f32_16x16x32_bf16(wp, h0, accP[j], 0, 0, 0);
            accQ[j] = __builtin_amdgcn_mfma_f32_16x16x32_bf16(wq, h0, accQ[j], 0, 0, 0);
        }
    }

    int node = m0 + lr;
    if (node < M) {
#pragma unroll
        for (int j = 0; j < 8; ++j) {
            int ch0 = j * 16 + kg * 4;
            f32x4 bq = *(const f32x4*)(be + ch0);     // fold edge-bias into Q
            if (MODE == 0) {
                *(bf16x4*)(HP + (size_t)node * 256 + 128 + ch0) = tobf4(accP[j]);
                *(bf16x4*)(Q1 + (size_t)node * 128 + ch0)       = tobf4(accQ[j] + bq);
            } else {
                *(bf16x4*)(P2 + (size_t)node * 128 + ch0) = tobf4(accP[j]);
                *(bf16x4*)(Q2 + (size_t)node * 128 + ch0) = tobf4(accQ[j] + bq);
            }
        }
    }
}

// ---------------- final edge op: e2 = relu(P2[u] + Q2[v]), Q2 pre-biased ----------------
__global__ __launch_bounds__(256) void k_add2(const __bf16* __restrict__ P,
                                              const __bf16* __restrict__ Q,
                                              const int* __restrict__ u,
                                              const int* __restrict__ v,
                                              float* __restrict__ out) {
    const int half = threadIdx.x >> 5;          // 0..7
    const int l = threadIdx.x & 31;
    const int e0 = blockIdx.x * 64 + half * 8;  // 64 edges/block, 8 per half-wave

    int uu[8], vv[8];
#pragma unroll
    for (int j = 0; j < 8; ++j) {
        uu[j] = __builtin_nontemporal_load(u + e0 + j);
        vv[j] = __builtin_nontemporal_load(v + e0 + j);
    }
    f32x4 pv[8], qv[8];
#pragma unroll
    for (int j = 0; j < 8; ++j) {
        pv[j] = ld4(P + (size_t)uu[j] * 128 + l * 4);
        qv[j] = ld4(Q + (size_t)vv[j] * 128 + l * 4);
    }
#pragma unroll
    for (int j = 0; j < 8; ++j) {
        f32x4 r = relu4(pv[j] + qv[j]);
        __builtin_nontemporal_store(r, (f32x4*)(out + (size_t)(e0 + j) * 128 + l * 4));
    }
}

extern "C" void kernel_launch(void* const* d_in, const int* in_sizes, int n_in,
                              void* d_out, int out_size, void* d_ws, size_t ws_size,
                              hipStream_t stream) {
    const float* nfeats = (const float*)d_in[0];
    const float* efeats = (const float*)d_in[1];
    const int*   u      = (const int*)d_in[2];
    const int*   v      = (const int*)d_in[3];
    const float* W1a = (const float*)d_in[4];
    const float* b1a = (const float*)d_in[5];
    const float* W1e = (const float*)d_in[6];
    const float* b1e = (const float*)d_in[7];
    const float* W2a = (const float*)d_in[8];
    const float* b2a = (const float*)d_in[9];
    const float* W2e = (const float*)d_in[10];
    const float* b2e = (const float*)d_in[11];

    float* h2f = (float*)d_out;                       // [NN,128] f32 (output 0)
    float* e2f = h2f + (size_t)NN * 128;              // [NE,128] f32 (output 1)

    // e2 region (409.6 MB) is scratch until k_add2 writes it
    char* eb = (char*)e2f;
    __bf16* Xbuf = (__bf16*)(eb);                     // [NN,256]  25,600,000 B (means only)
    __bf16* HP1  = (__bf16*)(eb + 25600000);          // [NN,256]  25,600,000 B (h1|P1)
    __bf16* Q1   = (__bf16*)(eb + 51200000);          // [NN,128]  12,800,000 B
    int2*   se   = (int2*)  (eb + 64000000);          // [NE]       6,400,000 B
    __bf16* nfbf = (__bf16*)(eb + 70400000);          // [NN,128]  12,800,000 B

    char* w = (char*)d_ws;
    int* cnt  = (int*)(w);                   // 200,000 B
    int* off  = (int*)(w + 200000);          // 200,004 B (padded)
    int* cur  = (int*)(w + 400016);          // 200,000 B
    int* bsum = (int*)(w + 600016);          // 196 B (pad 256)
    int* boff = (int*)(w + 600272);          // 196 B (pad 256)
    int* done = (int*)(w + 600528);          // 4 B (pad 16)
    __bf16* w1a = (__bf16*)(w + 600544);     // 98,304 B
    __bf16* w1e = (__bf16*)(w + 698848);     // 65,536 B
    __bf16* w2a = (__bf16*)(w + 764384);     // 98,304 B
    __bf16* w2e = (__bf16*)(w + 862688);     // 65,536 B
    __bf16* P2  = (__bf16*)(w + 928224);     // 12,800,000 B
    __bf16* Q2  = (__bf16*)(w + 13728224);   // 12,800,000 B (total ~26.5 MB)

    // prep + CSR build (scanB folded into scanA via last-block trick)
    k_prep<<<2048, 256, 0, stream>>>(cnt, done, W1a, w1a, W1e, w1e, W2a, w2a, W2e, w2e, nfeats, nfbf);
    k_count<<<1024, 256, 0, stream>>>(v, cnt);
    k_scanA<<<49, 1024, 0, stream>>>(cnt, bsum, boff, off, done);
    k_scanC<<<49, 1024, 0, stream>>>(cnt, boff, off, cur);
    k_fill<<<1024, 256, 0, stream>>>(u, v, cur, se);

    // layer 1
    k_agg1<<<NN / 4, 256, 0, stream>>>(nfbf, efeats, se, off, Xbuf);
    k_mlp_pq<0><<<(NN + 63) / 64, 256, 0, stream>>>(Xbuf, nfbf, w1a, b1a, w1e, b1e, HP1, Q1, nullptr, nullptr, nullptr, NN);

    // layer 2 (layer-1 edge-MLP fused into aggregation)
    k_agg2<<<NN / 4, 256, 0, stream>>>(HP1, Q1, se, off, Xbuf);
    k_mlp_pq<1><<<(NN + 63) / 64, 256, 0, stream>>>(Xbuf, HP1, w2a, b2a, w2e, b2e, nullptr, nullptr, h2f, P2, Q2, NN);
    k_add2<<<NE / 64, 256, 0, stream>>>(P2, Q2, u, v, e2f);
}

// Round 9
// 584.140 us; speedup vs baseline: 1.0713x; 1.0713x over previous
//
#include <hip/hip_runtime.h>
#include <hip/hip_bf16.h>
#include <stdint.h>
#include <stddef.h>

#define NN 50000
#define NE 800000

typedef __attribute__((ext_vector_type(8))) __bf16 bf16x8;
typedef __attribute__((ext_vector_type(4))) __bf16 bf16x4;
typedef __attribute__((ext_vector_type(2))) __bf16 bf16x2;
typedef __attribute__((ext_vector_type(4))) float  f32x4;

static __device__ __forceinline__ f32x4 ld4(const float* p)  { return *(const f32x4*)p; }
static __device__ __forceinline__ f32x4 ld4(const __bf16* p) {
    bf16x4 v = *(const bf16x4*)p;
    return (f32x4){(float)v[0], (float)v[1], (float)v[2], (float)v[3]};
}
static __device__ __forceinline__ f32x4 ld4_nt(const float* p) {
    return __builtin_nontemporal_load((const f32x4*)p);
}
static __device__ __forceinline__ f32x4 relu4(f32x4 a) {
    return (f32x4){fmaxf(a[0], 0.f), fmaxf(a[1], 0.f), fmaxf(a[2], 0.f), fmaxf(a[3], 0.f)};
}
static __device__ __forceinline__ bf16x4 tobf4(f32x4 a) {
    bf16x4 o; o[0] = (__bf16)a[0]; o[1] = (__bf16)a[1]; o[2] = (__bf16)a[2]; o[3] = (__bf16)a[3];
    return o;
}

// ---------------- prep: zero cnt/done + weights->bf16 + nfeats->bf16 ----------------
__global__ __launch_bounds__(256) void k_prep(int* __restrict__ cnt, int* __restrict__ done,
                                              const float* __restrict__ a, __bf16* __restrict__ oa,
                                              const float* __restrict__ b, __bf16* __restrict__ ob,
                                              const float* __restrict__ c, __bf16* __restrict__ oc,
                                              const float* __restrict__ d, __bf16* __restrict__ od,
                                              const float* __restrict__ nf, __bf16* __restrict__ nfbf) {
    int i = blockIdx.x * 256 + threadIdx.x;       // grid 2048 -> 524288 threads
    if (i == 0) *done = 0;
    if (i < NN) cnt[i] = 0;
    if (i < 128 * 384) { oa[i] = (__bf16)a[i]; oc[i] = (__bf16)c[i]; }
    if (i < 128 * 256) { ob[i] = (__bf16)b[i]; od[i] = (__bf16)d[i]; }
    int stride = gridDim.x * 256;
    for (int j = i; j < NN * 128 / 8; j += stride) {
        f32x4 x = __builtin_nontemporal_load((const f32x4*)(nf + (size_t)j * 8));
        f32x4 y = __builtin_nontemporal_load((const f32x4*)(nf + (size_t)j * 8 + 4));
        bf16x8 o;
        o[0] = (__bf16)x[0]; o[1] = (__bf16)x[1]; o[2] = (__bf16)x[2]; o[3] = (__bf16)x[3];
        o[4] = (__bf16)y[0]; o[5] = (__bf16)y[1]; o[6] = (__bf16)y[2]; o[7] = (__bf16)y[3];
        *(bf16x8*)(nfbf + (size_t)j * 8) = o;
    }
}

// ---------------- CSR build ----------------
__global__ __launch_bounds__(256) void k_count(const int* __restrict__ v, int* __restrict__ cnt) {
    int i = blockIdx.x * 256 + threadIdx.x;
    int stride = gridDim.x * 256;
    for (; i < NE; i += stride) atomicAdd(&cnt[v[i]], 1);
}

// stage A: per-1024-chunk sums; LAST block also scans the 49 partials
__global__ __launch_bounds__(1024) void k_scanA(const int* __restrict__ cnt,
                                                int* __restrict__ bsum,
                                                int* __restrict__ boff,
                                                int* __restrict__ off,
                                                int* __restrict__ done) {
    __shared__ int sh[1024];
    int b = blockIdx.x;                 // 0..48
    int t = threadIdx.x;
    int idx = b * 1024 + t;
    int val = (idx < NN) ? cnt[idx] : 0;
    sh[t] = val;
    __syncthreads();
    for (int d = 512; d > 0; d >>= 1) {
        if (t < d) sh[t] += sh[t + d];
        __syncthreads();
    }
    __shared__ int amLast;
    if (t == 0) {
        bsum[b] = sh[0];
        __threadfence();
        amLast = (atomicAdd(done, 1) == 48);
    }
    __syncthreads();
    if (amLast && t < 64) {
        __threadfence();
        int lane = t;
        int s = (lane < 49) ? bsum[lane] : 0;
        int incl = s;
        for (int d = 1; d < 64; d <<= 1) {
            int x = __shfl_up(incl, d);
            if (lane >= d) incl += x;
        }
        if (lane < 49) boff[lane] = incl - s;
        if (lane == 48) off[NN] = incl;
    }
}

__global__ __launch_bounds__(1024) void k_scanC(const int* __restrict__ cnt,
                                                const int* __restrict__ boff,
                                                int* __restrict__ off,
                                                int* __restrict__ cur) {
    __shared__ int sh[1024];
    int b = blockIdx.x;
    int t = threadIdx.x;
    int idx = b * 1024 + t;
    int val = (idx < NN) ? cnt[idx] : 0;
    sh[t] = val;
    __syncthreads();
    for (int d = 1; d < 1024; d <<= 1) {
        int x = (t >= d) ? sh[t - d] : 0;
        __syncthreads();
        sh[t] += x;
        __syncthreads();
    }
    int excl = sh[t] - val + boff[b];
    if (idx < NN) { off[idx] = excl; cur[idx] = excl; }
}

__global__ __launch_bounds__(256) void k_fill(const int* __restrict__ u,
                                              const int* __restrict__ v,
                                              int* __restrict__ cur,
                                              int2* __restrict__ se) {
    int i = blockIdx.x * 256 + threadIdx.x;
    int stride = gridDim.x * 256;
    for (; i < NE; i += stride) {
        int uu = __builtin_nontemporal_load(u + i);
        int vv = __builtin_nontemporal_load(v + i);
        int pos = atomicAdd(&cur[vv], 1);
        se[pos] = make_int2(uu, i);
    }
}

// ---------------- layer-1 aggregation: X[n][256] = [mean nf[u] | mean ef] ----------------
// (8-deep unroll — R6 shape; 16-deep regressed via VGPR/occupancy cliff)
__global__ __launch_bounds__(256) void k_agg1(const __bf16* __restrict__ nfbf,
                                              const float* __restrict__ ef,
                                              const int2* __restrict__ se,
                                              const int* __restrict__ off,
                                              __bf16* __restrict__ X) {
    const int wid  = threadIdx.x >> 6;
    const int lane = threadIdx.x & 63;
    const int n = blockIdx.x * 4 + wid;
    const int p0 = __builtin_amdgcn_readfirstlane(off[n]);
    const int p1 = __builtin_amdgcn_readfirstlane(off[n + 1]);
    const bool isE = lane >= 32;
    const int l = lane & 31;

    f32x4 acc = {0.f, 0.f, 0.f, 0.f};
    int p = p0;
    for (; p + 8 <= p1; p += 8) {
        int2 g[8];
#pragma unroll
        for (int j = 0; j < 8; ++j) g[j] = se[p + j];
        f32x4 t[8];
        if (isE) {
#pragma unroll
            for (int j = 0; j < 8; ++j) t[j] = ld4_nt(ef + (size_t)g[j].y * 128 + l * 4);
        } else {
#pragma unroll
            for (int j = 0; j < 8; ++j) t[j] = ld4(nfbf + (size_t)g[j].x * 128 + l * 4);
        }
#pragma unroll
        for (int j = 0; j < 8; ++j) acc += t[j];
    }
    for (; p < p1; ++p) {
        int2 g = se[p];
        acc += isE ? ld4_nt(ef + (size_t)g.y * 128 + l * 4)
                   : ld4(nfbf + (size_t)g.x * 128 + l * 4);
    }

    float inv = (p1 > p0) ? 1.f / (float)(p1 - p0) : 0.f;
    f32x4 m = {acc[0] * inv, acc[1] * inv, acc[2] * inv, acc[3] * inv};
    *(bf16x4*)(X + (size_t)n * 256 + (isE ? 128 : 0) + l * 4) = tobf4(m);
}

// ---------------- layer-2 aggregation, fused layer-1 edge-MLP ----------------
// HP1[n][256] = [h1[n] | P1[n]]; Q1 pre-biased.
// X2[n][256] = [mean h1[u], mean relu(P1[u] + Q1[n])]
__global__ __launch_bounds__(256) void k_agg2(const __bf16* __restrict__ HP1,
                                              const __bf16* __restrict__ Q1,
                                              const int2* __restrict__ se,
                                              const int* __restrict__ off,
                                              __bf16* __restrict__ X) {
    const int wid  = threadIdx.x >> 6;
    const int lane = threadIdx.x & 63;
    const int n = blockIdx.x * 4 + wid;
    const int p0 = __builtin_amdgcn_readfirstlane(off[n]);
    const int p1 = __builtin_amdgcn_readfirstlane(off[n + 1]);
    const bool isE = lane >= 32;                 // lanes 32-63 own the P-half of the row
    const int l = lane & 31;

    f32x4 qb = ld4(Q1 + (size_t)n * 128 + l * 4);   // bias already folded

    f32x4 acc = {0.f, 0.f, 0.f, 0.f};
    int p = p0;
    for (; p + 8 <= p1; p += 8) {
        int g[8];
#pragma unroll
        for (int j = 0; j < 8; ++j) g[j] = se[p + j].x;
        f32x4 t[8];
#pragma unroll
        for (int j = 0; j < 8; ++j) t[j] = ld4(HP1 + (size_t)g[j] * 256 + lane * 4);
#pragma unroll
        for (int j = 0; j < 8; ++j) acc += isE ? relu4(t[j] + qb) : t[j];
    }
    for (; p < p1; ++p) {
        int g = se[p].x;
        f32x4 t = ld4(HP1 + (size_t)g * 256 + lane * 4);
        acc += isE ? relu4(t + qb) : t;
    }

    float inv = (p1 > p0) ? 1.f / (float)(p1 - p0) : 0.f;
    f32x4 m = {acc[0] * inv, acc[1] * inv, acc[2] * inv, acc[3] * inv};
    *(bf16x4*)(X + (size_t)n * 256 + (isE ? 128 : 0) + l * 4) = tobf4(m);
}

// ---------------- fused node MLP + P/Q projection (K-split: self + means) ----------------
// MODE 0: S=nfbf (SS=128); h,P -> HP1; Q+be -> Q1
// MODE 1: S=HP1 h-half (SS=256); h -> Hf f32 nt; P -> P2, Q+be -> Q2
template <int MODE>
__global__ __launch_bounds__(256) void k_mlp_pq(const __bf16* __restrict__ X,
                                                const __bf16* __restrict__ S,
                                                const __bf16* __restrict__ Wa,
                                                const float* __restrict__ ba,
                                                const __bf16* __restrict__ We,
                                                const float* __restrict__ be,
                                                __bf16* __restrict__ HP,
                                                __bf16* __restrict__ Q1,
                                                float* __restrict__ Hf,
                                                __bf16* __restrict__ P2,
                                                __bf16* __restrict__ Q2,
                                                int M) {
    const int K = 384;
    const int SS = (MODE == 0) ? 128 : 256;
    const int wave = threadIdx.x >> 6;
    const int lane = threadIdx.x & 63;
    const int m0 = blockIdx.x * 64 + wave * 16;
    const int lr = lane & 15;
    const int kg = lane >> 4;

    __shared__ __bf16 hlds[4 * 16 * 136];   // per-wave [16][136] bf16
    __bf16* my = hlds + wave * 16 * 136;

    f32x4 acc[8];
#pragma unroll
    for (int j = 0; j < 8; ++j) acc[j] = (f32x4){0.f, 0.f, 0.f, 0.f};

    int r0 = m0 + lr; if (r0 > M - 1) r0 = M - 1;
    const __bf16* ps0 = S + (size_t)r0 * SS + 8 * kg;   // self features
    const __bf16* px0 = X + (size_t)r0 * 256 + 8 * kg;  // mean features
    const __bf16* pwa = Wa + (size_t)lr * K + 8 * kg;

    // self part: Wa cols 0-127
#pragma unroll
    for (int k0 = 0; k0 < 128; k0 += 32) {
        bf16x8 x0 = *(const bf16x8*)(ps0 + k0);
#pragma unroll
        for (int j = 0; j < 8; ++j) {
            bf16x8 w = *(const bf16x8*)(pwa + (size_t)j * 16 * K + k0);
            acc[j] = __builtin_amdgcn_mfma_f32_16x16x32_bf16(w, x0, acc[j], 0, 0, 0);
        }
    }
    // mean part: Wa cols 128-383
#pragma unroll
    for (int k0 = 0; k0 < 256; k0 += 32) {
        bf16x8 x0 = *(const bf16x8*)(px0 + k0);
#pragma unroll
        for (int j = 0; j < 8; ++j) {
            bf16x8 w = *(const bf16x8*)(pwa + (size_t)j * 16 * K + 128 + k0);
            acc[j] = __builtin_amdgcn_mfma_f32_16x16x32_bf16(w, x0, acc[j], 0, 0, 0);
        }
    }

    // epilogue: store h + stage into LDS for the P/Q GEMM
    {
        int node = m0 + lr;
#pragma unroll
        for (int j = 0; j < 8; ++j) {
            int ch0 = j * 16 + kg * 4;
            f32x4 bb = *(const f32x4*)(ba + ch0);
            f32x4 val = relu4(acc[j] + bb);
            bf16x4 vb = tobf4(val);
            *(bf16x4*)(my + lr * 136 + ch0) = vb;
            if (node < M) {
                if (MODE == 0) *(bf16x4*)(HP + (size_t)node * 256 + ch0) = vb;
                else __builtin_nontemporal_store(val, (f32x4*)(Hf + (size_t)node * 128 + ch0));
            }
        }
    }
    __syncthreads();

    // second GEMM: P/Q from LDS h-tile (16 rows)
    f32x4 accP[8], accQ[8];
#pragma unroll
    for (int j = 0; j < 8; ++j) { accP[j] = (f32x4){0,0,0,0}; accQ[j] = (f32x4){0,0,0,0}; }

    const __bf16* pwe = We + (size_t)lr * 256 + 8 * kg;
#pragma unroll
    for (int k0 = 0; k0 < 128; k0 += 32) {
        bf16x8 h0 = *(const bf16x8*)(my + lr * 136 + k0 + 8 * kg);
#pragma unroll
        for (int j = 0; j < 8; ++j) {
            bf16x8 wp = *(const bf16x8*)(pwe + (size_t)j * 16 * 256 + k0);
            bf16x8 wq = *(const bf16x8*)(pwe + (size_t)j * 16 * 256 + 128 + k0);
            accP[j] = __builtin_amdgcn_mfma_f32_16x16x32_bf16(wp, h0, accP[j], 0, 0, 0);
            accQ[j] = __builtin_amdgcn_mfma_f32_16x16x32_bf16(wq, h0, accQ[j], 0, 0, 0);
        }
    }

    int node = m0 + lr;
    if (node < M) {
#pragma unroll
        for (int j = 0; j < 8; ++j) {
            int ch0 = j * 16 + kg * 4;
            f32x4 bq = *(const f32x4*)(be + ch0);     // fold edge-bias into Q
            if (MODE == 0) {
                *(bf16x4*)(HP + (size_t)node * 256 + 128 + ch0) = tobf4(accP[j]);
                *(bf16x4*)(Q1 + (size_t)node * 128 + ch0)       = tobf4(accQ[j] + bq);
            } else {
                *(bf16x4*)(P2 + (size_t)node * 128 + ch0) = tobf4(accP[j]);
                *(bf16x4*)(Q2 + (size_t)node * 128 + ch0) = tobf4(accQ[j] + bq);
            }
        }
    }
}

// ---------------- final edge op: e2 = relu(P2[u] + Q2[v]), Q2 pre-biased ----------------
__global__ __launch_bounds__(256) void k_add2(const __bf16* __restrict__ P,
                                              const __bf16* __restrict__ Q,
                                              const int* __restrict__ u,
                                              const int* __restrict__ v,
                                              float* __restrict__ out) {
    const int half = threadIdx.x >> 5;          // 0..7
    const int l = threadIdx.x & 31;
    const int e0 = blockIdx.x * 64 + half * 8;  // 64 edges/block, 8 per half-wave

    int uu[8], vv[8];
#pragma unroll
    for (int j = 0; j < 8; ++j) {
        uu[j] = __builtin_nontemporal_load(u + e0 + j);
        vv[j] = __builtin_nontemporal_load(v + e0 + j);
    }
    f32x4 pv[8], qv[8];
#pragma unroll
    for (int j = 0; j < 8; ++j) {
        pv[j] = ld4(P + (size_t)uu[j] * 128 + l * 4);
        qv[j] = ld4(Q + (size_t)vv[j] * 128 + l * 4);
    }
#pragma unroll
    for (int j = 0; j < 8; ++j) {
        f32x4 r = relu4(pv[j] + qv[j]);
        __builtin_nontemporal_store(r, (f32x4*)(out + (size_t)(e0 + j) * 128 + l * 4));
    }
}

extern "C" void kernel_launch(void* const* d_in, const int* in_sizes, int n_in,
                              void* d_out, int out_size, void* d_ws, size_t ws_size,
                              hipStream_t stream) {
    const float* nfeats = (const float*)d_in[0];
    const float* efeats = (const float*)d_in[1];
    const int*   u      = (const int*)d_in[2];
    const int*   v      = (const int*)d_in[3];
    const float* W1a = (const float*)d_in[4];
    const float* b1a = (const float*)d_in[5];
    const float* W1e = (const float*)d_in[6];
    const float* b1e = (const float*)d_in[7];
    const float* W2a = (const float*)d_in[8];
    const float* b2a = (const float*)d_in[9];
    const float* W2e = (const float*)d_in[10];
    const float* b2e = (const float*)d_in[11];

    float* h2f = (float*)d_out;                       // [NN,128] f32 (output 0)
    float* e2f = h2f + (size_t)NN * 128;              // [NE,128] f32 (output 1)

    // e2 region (409.6 MB) is scratch until k_add2 writes it
    char* eb = (char*)e2f;
    __bf16* Xbuf = (__bf16*)(eb);                     // [NN,256]  25,600,000 B (means only)
    __bf16* HP1  = (__bf16*)(eb + 25600000);          // [NN,256]  25,600,000 B (h1|P1)
    __bf16* Q1   = (__bf16*)(eb + 51200000);          // [NN,128]  12,800,000 B
    int2*   se   = (int2*)  (eb + 64000000);          // [NE]       6,400,000 B
    __bf16* nfbf = (__bf16*)(eb + 70400000);          // [NN,128]  12,800,000 B

    char* w = (char*)d_ws;
    int* cnt  = (int*)(w);                   // 200,000 B
    int* off  = (int*)(w + 200000);          // 200,004 B (padded)
    int* cur  = (int*)(w + 400016);          // 200,000 B
    int* bsum = (int*)(w + 600016);          // 196 B (pad 256)
    int* boff = (int*)(w + 600272);          // 196 B (pad 256)
    int* done = (int*)(w + 600528);          // 4 B (pad 16)
    __bf16* w1a = (__bf16*)(w + 600544);     // 98,304 B
    __bf16* w1e = (__bf16*)(w + 698848);     // 65,536 B
    __bf16* w2a = (__bf16*)(w + 764384);     // 98,304 B
    __bf16* w2e = (__bf16*)(w + 862688);     // 65,536 B
    __bf16* P2  = (__bf16*)(w + 928224);     // 12,800,000 B
    __bf16* Q2  = (__bf16*)(w + 13728224);   // 12,800,000 B (total ~26.5 MB)

    // prep + CSR build
    k_prep<<<2048, 256, 0, stream>>>(cnt, done, W1a, w1a, W1e, w1e, W2a, w2a, W2e, w2e, nfeats, nfbf);
    k_count<<<1024, 256, 0, stream>>>(v, cnt);
    k_scanA<<<49, 1024, 0, stream>>>(cnt, bsum, boff, off, done);
    k_scanC<<<49, 1024, 0, stream>>>(cnt, boff, off, cur);
    k_fill<<<1024, 256, 0, stream>>>(u, v, cur, se);

    // layer 1
    k_agg1<<<NN / 4, 256, 0, stream>>>(nfbf, efeats, se, off, Xbuf);
    k_mlp_pq<0><<<(NN + 63) / 64, 256, 0, stream>>>(Xbuf, nfbf, w1a, b1a, w1e, b1e, HP1, Q1, nullptr, nullptr, nullptr, NN);

    // layer 2 (layer-1 edge-MLP fused into aggregation)
    k_agg2<<<NN / 4, 256, 0, stream>>>(HP1, Q1, se, off, Xbuf);
    k_mlp_pq<1><<<(NN + 63) / 64, 256, 0, stream>>>(Xbuf, HP1, w2a, b2a, w2e, b2e, nullptr, nullptr, h2f, P2, Q2, NN);
    k_add2<<<NE / 64, 256, 0, stream>>>(P2, Q2, u, v, e2f);
}

// Round 11
// 546.948 us; speedup vs baseline: 1.1441x; 1.0680x over previous
//
#include <hip/hip_runtime.h>
#include <hip/hip_bf16.h>
#include <stdint.h>
#include <stddef.h>

#define NN 50000
#define NE 800000

typedef __attribute__((ext_vector_type(8))) __bf16 bf16x8;
typedef __attribute__((ext_vector_type(4))) __bf16 bf16x4;
typedef __attribute__((ext_vector_type(2))) __bf16 bf16x2;
typedef __attribute__((ext_vector_type(4))) float  f32x4;

static __device__ __forceinline__ f32x4 ld4(const float* p)  { return *(const f32x4*)p; }
static __device__ __forceinline__ f32x4 ld4(const __bf16* p) {
    bf16x4 v = *(const bf16x4*)p;
    return (f32x4){(float)v[0], (float)v[1], (float)v[2], (float)v[3]};
}
static __device__ __forceinline__ f32x4 ld4_nt(const float* p) {
    return __builtin_nontemporal_load((const f32x4*)p);
}
static __device__ __forceinline__ f32x4 relu4(f32x4 a) {
    return (f32x4){fmaxf(a[0], 0.f), fmaxf(a[1], 0.f), fmaxf(a[2], 0.f), fmaxf(a[3], 0.f)};
}
static __device__ __forceinline__ bf16x4 tobf4(f32x4 a) {
    bf16x4 o; o[0] = (__bf16)a[0]; o[1] = (__bf16)a[1]; o[2] = (__bf16)a[2]; o[3] = (__bf16)a[3];
    return o;
}

// ---------------- prep: zero cnt/flags + weights->bf16 + nfeats->bf16 ----------------
__global__ __launch_bounds__(256) void k_prep(int* __restrict__ cnt, int* __restrict__ flags,
                                              const float* __restrict__ a, __bf16* __restrict__ oa,
                                              const float* __restrict__ b, __bf16* __restrict__ ob,
                                              const float* __restrict__ c, __bf16* __restrict__ oc,
                                              const float* __restrict__ d, __bf16* __restrict__ od,
                                              const float* __restrict__ nf, __bf16* __restrict__ nfbf) {
    int i = blockIdx.x * 256 + threadIdx.x;       // grid 2048 -> 524288 threads
    if (i < 2) flags[i] = 0;
    if (i < NN) cnt[i] = 0;
    if (i < 128 * 384) { oa[i] = (__bf16)a[i]; oc[i] = (__bf16)c[i]; }
    if (i < 128 * 256) { ob[i] = (__bf16)b[i]; od[i] = (__bf16)d[i]; }
    int stride = gridDim.x * 256;
    for (int j = i; j < NN * 128 / 8; j += stride) {
        f32x4 x = __builtin_nontemporal_load((const f32x4*)(nf + (size_t)j * 8));
        f32x4 y = __builtin_nontemporal_load((const f32x4*)(nf + (size_t)j * 8 + 4));
        bf16x8 o;
        o[0] = (__bf16)x[0]; o[1] = (__bf16)x[1]; o[2] = (__bf16)x[2]; o[3] = (__bf16)x[3];
        o[4] = (__bf16)y[0]; o[5] = (__bf16)y[1]; o[6] = (__bf16)y[2]; o[7] = (__bf16)y[3];
        *(bf16x8*)(nfbf + (size_t)j * 8) = o;
    }
}

// ---------------- CSR build ----------------
__global__ __launch_bounds__(256) void k_count(const int* __restrict__ v, int* __restrict__ cnt) {
    int i = blockIdx.x * 256 + threadIdx.x;
    int stride = gridDim.x * 256;
    for (; i < NE; i += stride) {
        int vv = __builtin_nontemporal_load(v + i);
        atomicAdd(&cnt[vv], 1);
    }
}

// stage A: per-1024-chunk sums; LAST block also scans the 49 partials (R8-proven)
__global__ __launch_bounds__(1024) void k_scanA(const int* __restrict__ cnt,
                                                int* __restrict__ bsum,
                                                int* __restrict__ boff,
                                                int* __restrict__ off,
                                                int* __restrict__ done) {
    __shared__ int sh[1024];
    int b = blockIdx.x;                 // 0..48
    int t = threadIdx.x;
    int idx = b * 1024 + t;
    int val = (idx < NN) ? cnt[idx] : 0;
    sh[t] = val;
    __syncthreads();
    for (int d = 512; d > 0; d >>= 1) {
        if (t < d) sh[t] += sh[t + d];
        __syncthreads();
    }
    __shared__ int amLast;
    if (t == 0) {
        bsum[b] = sh[0];
        __threadfence();
        amLast = (atomicAdd(done, 1) == 48);
    }
    __syncthreads();
    if (amLast && t < 64) {
        __threadfence();
        int lane = t;
        int s = (lane < 49) ? bsum[lane] : 0;
        int incl = s;
        for (int d = 1; d < 64; d <<= 1) {
            int x = __shfl_up(incl, d);
            if (lane >= d) incl += x;
        }
        if (lane < 49) boff[lane] = incl - s;
        if (lane == 48) off[NN] = incl;
    }
}

__global__ __launch_bounds__(1024) void k_scanC(const int* __restrict__ cnt,
                                                const int* __restrict__ boff,
                                                int* __restrict__ off,
                                                int* __restrict__ cur) {
    __shared__ int sh[1024];
    int b = blockIdx.x;
    int t = threadIdx.x;
    int idx = b * 1024 + t;
    int val = (idx < NN) ? cnt[idx] : 0;
    sh[t] = val;
    __syncthreads();
    for (int d = 1; d < 1024; d <<= 1) {
        int x = (t >= d) ? sh[t - d] : 0;
        __syncthreads();
        sh[t] += x;
        __syncthreads();
    }
    int excl = sh[t] - val + boff[b];
    if (idx < NN) { off[idx] = excl; cur[idx] = excl; }
}

__global__ __launch_bounds__(256) void k_fill(const int* __restrict__ u,
                                              const int* __restrict__ v,
                                              int* __restrict__ cur,
                                              int2* __restrict__ se) {
    int i = blockIdx.x * 256 + threadIdx.x;
    int stride = gridDim.x * 256;
    for (; i < NE; i += stride) {
        int uu = __builtin_nontemporal_load(u + i);
        int vv = __builtin_nontemporal_load(v + i);
        int pos = atomicAdd(&cur[vv], 1);
        se[pos] = make_int2(uu, i);
    }
}

// ---------------- layer-1 aggregation: X[n][256] = [mean nf[u] | mean ef] ----------------
__global__ __launch_bounds__(256) void k_agg1(const __bf16* __restrict__ nfbf,
                                              const float* __restrict__ ef,
                                              const int2* __restrict__ se,
                                              const int* __restrict__ off,
                                              __bf16* __restrict__ X) {
    const int wid  = threadIdx.x >> 6;
    const int lane = threadIdx.x & 63;
    const int n = blockIdx.x * 4 + wid;
    const int p0 = __builtin_amdgcn_readfirstlane(off[n]);
    const int p1 = __builtin_amdgcn_readfirstlane(off[n + 1]);
    const bool isE = lane >= 32;
    const int l = lane & 31;

    f32x4 acc = {0.f, 0.f, 0.f, 0.f};
    int p = p0;
    for (; p + 8 <= p1; p += 8) {
        int2 g[8];
#pragma unroll
        for (int j = 0; j < 8; ++j) g[j] = se[p + j];
        f32x4 t[8];
        if (isE) {
#pragma unroll
            for (int j = 0; j < 8; ++j) t[j] = ld4_nt(ef + (size_t)g[j].y * 128 + l * 4);
        } else {
#pragma unroll
            for (int j = 0; j < 8; ++j) t[j] = ld4(nfbf + (size_t)g[j].x * 128 + l * 4);
        }
#pragma unroll
        for (int j = 0; j < 8; ++j) acc += t[j];
    }
    for (; p < p1; ++p) {
        int2 g = se[p];
        acc += isE ? ld4_nt(ef + (size_t)g.y * 128 + l * 4)
                   : ld4(nfbf + (size_t)g.x * 128 + l * 4);
    }

    float inv = (p1 > p0) ? 1.f / (float)(p1 - p0) : 0.f;
    f32x4 m = {acc[0] * inv, acc[1] * inv, acc[2] * inv, acc[3] * inv};
    *(bf16x4*)(X + (size_t)n * 256 + (isE ? 128 : 0) + l * 4) = tobf4(m);
}

// ---------------- layer-2 aggregation, fused layer-1 edge-MLP ----------------
__global__ __launch_bounds__(256) void k_agg2(const __bf16* __restrict__ HP1,
                                              const __bf16* __restrict__ Q1,
                                              const int2* __restrict__ se,
                                              const int* __restrict__ off,
                                              __bf16* __restrict__ X) {
    const int wid  = threadIdx.x >> 6;
    const int lane = threadIdx.x & 63;
    const int n = blockIdx.x * 4 + wid;
    const int p0 = __builtin_amdgcn_readfirstlane(off[n]);
    const int p1 = __builtin_amdgcn_readfirstlane(off[n + 1]);
    const bool isE = lane >= 32;                 // lanes 32-63 own the P-half of the row
    const int l = lane & 31;

    f32x4 qb = ld4(Q1 + (size_t)n * 128 + l * 4);   // bias already folded

    f32x4 acc = {0.f, 0.f, 0.f, 0.f};
    int p = p0;
    for (; p + 8 <= p1; p += 8) {
        int g[8];
#pragma unroll
        for (int j = 0; j < 8; ++j) g[j] = se[p + j].x;
        f32x4 t[8];
#pragma unroll
        for (int j = 0; j < 8; ++j) t[j] = ld4(HP1 + (size_t)g[j] * 256 + lane * 4);
#pragma unroll
        for (int j = 0; j < 8; ++j) acc += isE ? relu4(t[j] + qb) : t[j];
    }
    for (; p < p1; ++p) {
        int g = se[p].x;
        f32x4 t = ld4(HP1 + (size_t)g * 256 + lane * 4);
        acc += isE ? relu4(t + qb) : t;
    }

    float inv = (p1 > p0) ? 1.f / (float)(p1 - p0) : 0.f;
    f32x4 m = {acc[0] * inv, acc[1] * inv, acc[2] * inv, acc[3] * inv};
    *(bf16x4*)(X + (size_t)n * 256 + (isE ? 128 : 0) + l * 4) = tobf4(m);
}

// ---------------- fused node MLP + P/Q projection (K-split: self + means) ----------------
template <int MODE>
__global__ __launch_bounds__(256) void k_mlp_pq(const __bf16* __restrict__ X,
                                                const __bf16* __restrict__ S,
                                                const __bf16* __restrict__ Wa,
                                                const float* __restrict__ ba,
                                                const __bf16* __restrict__ We,
                                                const float* __restrict__ be,
                                                __bf16* __restrict__ HP,
                                                __bf16* __restrict__ Q1,
                                                float* __restrict__ Hf,
                                                __bf16* __restrict__ P2,
                                                __bf16* __restrict__ Q2,
                                                int M) {
    const int K = 384;
    const int SS = (MODE == 0) ? 128 : 256;
    const int wave = threadIdx.x >> 6;
    const int lane = threadIdx.x & 63;
    const int m0 = blockIdx.x * 64 + wave * 16;
    const int lr = lane & 15;
    const int kg = lane >> 4;

    __shared__ __bf16 hlds[4 * 16 * 136];   // per-wave [16][136] bf16
    __bf16* my = hlds + wave * 16 * 136;

    f32x4 acc[8];
#pragma unroll
    for (int j = 0; j < 8; ++j) acc[j] = (f32x4){0.f, 0.f, 0.f, 0.f};

    int r0 = m0 + lr; if (r0 > M - 1) r0 = M - 1;
    const __bf16* ps0 = S + (size_t)r0 * SS + 8 * kg;   // self features
    const __bf16* px0 = X + (size_t)r0 * 256 + 8 * kg;  // mean features
    const __bf16* pwa = Wa + (size_t)lr * K + 8 * kg;

    // self part: Wa cols 0-127
#pragma unroll
    for (int k0 = 0; k0 < 128; k0 += 32) {
        bf16x8 x0 = *(const bf16x8*)(ps0 + k0);
#pragma unroll
        for (int j = 0; j < 8; ++j) {
            bf16x8 w = *(const bf16x8*)(pwa + (size_t)j * 16 * K + k0);
            acc[j] = __builtin_amdgcn_mfma_f32_16x16x32_bf16(w, x0, acc[j], 0, 0, 0);
        }
    }
    // mean part: Wa cols 128-383
#pragma unroll
    for (int k0 = 0; k0 < 256; k0 += 32) {
        bf16x8 x0 = *(const bf16x8*)(px0 + k0);
#pragma unroll
        for (int j = 0; j < 8; ++j) {
            bf16x8 w = *(const bf16x8*)(pwa + (size_t)j * 16 * K + 128 + k0);
            acc[j] = __builtin_amdgcn_mfma_f32_16x16x32_bf16(w, x0, acc[j], 0, 0, 0);
        }
    }

    // epilogue: store h + stage into LDS for the P/Q GEMM
    {
        int node = m0 + lr;
#pragma unroll
        for (int j = 0; j < 8; ++j) {
            int ch0 = j * 16 + kg * 4;
            f32x4 bb = *(const f32x4*)(ba + ch0);
            f32x4 val = relu4(acc[j] + bb);
            bf16x4 vb = tobf4(val);
            *(bf16x4*)(my + lr * 136 + ch0) = vb;
            if (node < M) {
                if (MODE == 0) *(bf16x4*)(HP + (size_t)node * 256 + ch0) = vb;
                else __builtin_nontemporal_store(val, (f32x4*)(Hf + (size_t)node * 128 + ch0));
            }
        }
    }
    __syncthreads();

    // second GEMM: P/Q from LDS h-tile (16 rows)
    f32x4 accP[8], accQ[8];
#pragma unroll
    for (int j = 0; j < 8; ++j) { accP[j] = (f32x4){0,0,0,0}; accQ[j] = (f32x4){0,0,0,0}; }

    const __bf16* pwe = We + (size_t)lr * 256 + 8 * kg;
#pragma unroll
    for (int k0 = 0; k0 < 128; k0 += 32) {
        bf16x8 h0 = *(const bf16x8*)(my + lr * 136 + k0 + 8 * kg);
#pragma unroll
        for (int j = 0; j < 8; ++j) {
            bf16x8 wp = *(const bf16x8*)(pwe + (size_t)j * 16 * 256 + k0);
            bf16x8 wq = *(const bf16x8*)(pwe + (size_t)j * 16 * 256 + 128 + k0);
            accP[j] = __builtin_amdgcn_mfma_f32_16x16x32_bf16(wp, h0, accP[j], 0, 0, 0);
            accQ[j] = __builtin_amdgcn_mfma_f32_16x16x32_bf16(wq, h0, accQ[j], 0, 0, 0);
        }
    }

    int node = m0 + lr;
    if (node < M) {
#pragma unroll
        for (int j = 0; j < 8; ++j) {
            int ch0 = j * 16 + kg * 4;
            f32x4 bq = *(const f32x4*)(be + ch0);     // fold edge-bias into Q
            if (MODE == 0) {
                *(bf16x4*)(HP + (size_t)node * 256 + 128 + ch0) = tobf4(accP[j]);
                *(bf16x4*)(Q1 + (size_t)node * 128 + ch0)       = tobf4(accQ[j] + bq);
            } else {
                *(bf16x4*)(P2 + (size_t)node * 128 + ch0) = tobf4(accP[j]);
                *(bf16x4*)(Q2 + (size_t)node * 128 + ch0) = tobf4(accQ[j] + bq);
            }
        }
    }
}

// ---------------- final edge op, CSR order (se must NOT alias e2 region!) ----------------
__global__ __launch_bounds__(256) void k_add2_csr(const __bf16* __restrict__ P,
                                                  const __bf16* __restrict__ Q,
                                                  const int2* __restrict__ se,
                                                  const int* __restrict__ off,
                                                  float* __restrict__ out) {
    const int wid  = threadIdx.x >> 6;
    const int lane = threadIdx.x & 63;
    const int n = blockIdx.x * 4 + wid;
    const int p0 = __builtin_amdgcn_readfirstlane(off[n]);
    const int p1 = __builtin_amdgcn_readfirstlane(off[n + 1]);
    const int half = lane >> 5;
    const int l = lane & 31;

    f32x4 qb = ld4(Q + (size_t)n * 128 + l * 4);  // pre-biased, wave-uniform node

    int p = p0 + half;
    for (; p + 6 < p1; p += 8) {                  // 4 edges per half-wave per iter
        int2 g[4];
#pragma unroll
        for (int j = 0; j < 4; ++j) g[j] = se[p + 2 * j];
        f32x4 pv[4];
#pragma unroll
        for (int j = 0; j < 4; ++j) pv[j] = ld4(P + (size_t)g[j].x * 128 + l * 4);
#pragma unroll
        for (int j = 0; j < 4; ++j) {
            f32x4 r = relu4(pv[j] + qb);
            __builtin_nontemporal_store(r, (f32x4*)(out + (size_t)g[j].y * 128 + l * 4));
        }
    }
    for (; p < p1; p += 2) {
        int2 g = se[p];
        f32x4 pv = ld4(P + (size_t)g.x * 128 + l * 4);
        f32x4 r = relu4(pv + qb);
        __builtin_nontemporal_store(r, (f32x4*)(out + (size_t)g.y * 128 + l * 4));
    }
}

// fallback (R8-proven): sequential edge order, reads u/v, no se dependency
__global__ __launch_bounds__(256) void k_add2_seq(const __bf16* __restrict__ P,
                                                  const __bf16* __restrict__ Q,
                                                  const int* __restrict__ u,
                                                  const int* __restrict__ v,
                                                  float* __restrict__ out) {
    const int half = threadIdx.x >> 5;
    const int l = threadIdx.x & 31;
    const int e0 = blockIdx.x * 64 + half * 8;

    int uu[8], vv[8];
#pragma unroll
    for (int j = 0; j < 8; ++j) {
        uu[j] = __builtin_nontemporal_load(u + e0 + j);
        vv[j] = __builtin_nontemporal_load(v + e0 + j);
    }
    f32x4 pv[8], qv[8];
#pragma unroll
    for (int j = 0; j < 8; ++j) {
        pv[j] = ld4(P + (size_t)uu[j] * 128 + l * 4);
        qv[j] = ld4(Q + (size_t)vv[j] * 128 + l * 4);
    }
#pragma unroll
    for (int j = 0; j < 8; ++j) {
        f32x4 r = relu4(pv[j] + qv[j]);
        __builtin_nontemporal_store(r, (f32x4*)(out + (size_t)(e0 + j) * 128 + l * 4));
    }
}

extern "C" void kernel_launch(void* const* d_in, const int* in_sizes, int n_in,
                              void* d_out, int out_size, void* d_ws, size_t ws_size,
                              hipStream_t stream) {
    const float* nfeats = (const float*)d_in[0];
    const float* efeats = (const float*)d_in[1];
    const int*   u      = (const int*)d_in[2];
    const int*   v      = (const int*)d_in[3];
    const float* W1a = (const float*)d_in[4];
    const float* b1a = (const float*)d_in[5];
    const float* W1e = (const float*)d_in[6];
    const float* b1e = (const float*)d_in[7];
    const float* W2a = (const float*)d_in[8];
    const float* b2a = (const float*)d_in[9];
    const float* W2e = (const float*)d_in[10];
    const float* b2e = (const float*)d_in[11];

    float* h2f = (float*)d_out;                       // [NN,128] f32 (output 0)
    float* e2f = h2f + (size_t)NN * 128;              // [NE,128] f32 (output 1)

    // e2-region scratch: ALL dead before k_add2 runs (invariant!)
    char* eb = (char*)e2f;
    __bf16* Xbuf = (__bf16*)(eb);                     // [NN,256]  25,600,000 B
    __bf16* HP1  = (__bf16*)(eb + 25600000);          // [NN,256]  25,600,000 B (h1|P1)
    __bf16* Q1   = (__bf16*)(eb + 51200000);          // [NN,128]  12,800,000 B
    __bf16* nfbf = (__bf16*)(eb + 64000000);          // [NN,128]  12,800,000 B

    char* w = (char*)d_ws;
    int* cnt   = (int*)(w);                  // 200,000 B
    int* off   = (int*)(w + 200000);         // 200,004 B (padded)
    int* cur   = (int*)(w + 400016);         // 200,000 B
    int* bsum  = (int*)(w + 600016);         // 196 B (pad 256)
    int* boff  = (int*)(w + 600272);         // 196 B (pad 256)
    int* flags = (int*)(w + 600528);         // 8 B (pad 16)
    __bf16* w1a = (__bf16*)(w + 600544);     // 98,304 B
    __bf16* w1e = (__bf16*)(w + 698848);     // 65,536 B
    __bf16* w2a = (__bf16*)(w + 764384);     // 98,304 B
    __bf16* w2e = (__bf16*)(w + 862688);     // 65,536 B
    __bf16* P2  = (__bf16*)(w + 928224);     // 12,800,000 B
    __bf16* Q2  = (__bf16*)(w + 13728224);   // 12,800,000 B
    int2*  seWS = (int2*) (w + 26528224);    //  6,400,000 B -> total 32,928,224 B

    // se in d_ws if it fits (needed so k_add2_csr's scattered e2 writes can't clobber it);
    // otherwise se goes in the e2 region and we use the sequential add2 (R8 path).
    bool csr_add = ws_size >= (size_t)32928224;
    int2* se = csr_add ? seWS : (int2*)(eb + 76800000);

    // prep + CSR build
    k_prep<<<2048, 256, 0, stream>>>(cnt, flags, W1a, w1a, W1e, w1e, W2a, w2a, W2e, w2e, nfeats, nfbf);
    k_count<<<1024, 256, 0, stream>>>(v, cnt);
    k_scanA<<<49, 1024, 0, stream>>>(cnt, bsum, boff, off, flags);
    k_scanC<<<49, 1024, 0, stream>>>(cnt, boff, off, cur);
    k_fill<<<1024, 256, 0, stream>>>(u, v, cur, se);

    // layer 1
    k_agg1<<<NN / 4, 256, 0, stream>>>(nfbf, efeats, se, off, Xbuf);
    k_mlp_pq<0><<<(NN + 63) / 64, 256, 0, stream>>>(Xbuf, nfbf, w1a, b1a, w1e, b1e, HP1, Q1, nullptr, nullptr, nullptr, NN);

    // layer 2 (layer-1 edge-MLP fused into aggregation)
    k_agg2<<<NN / 4, 256, 0, stream>>>(HP1, Q1, se, off, Xbuf);
    k_mlp_pq<1><<<(NN + 63) / 64, 256, 0, stream>>>(Xbuf, HP1, w2a, b2a, w2e, b2e, nullptr, nullptr, h2f, P2, Q2, NN);

    // final edge op
    if (csr_add) k_add2_csr<<<NN / 4, 256, 0, stream>>>(P2, Q2, se, off, e2f);
    else         k_add2_seq<<<NE / 64, 256, 0, stream>>>(P2, Q2, u, v, e2f);
}

// Round 12
// 525.500 us; speedup vs baseline: 1.1908x; 1.0408x over previous
//
#include <hip/hip_runtime.h>
#include <hip/hip_bf16.h>
#include <stdint.h>
#include <stddef.h>

#define NN 50000
#define NE 800000

typedef __attribute__((ext_vector_type(8))) __bf16 bf16x8;
typedef __attribute__((ext_vector_type(4))) __bf16 bf16x4;
typedef __attribute__((ext_vector_type(2))) __bf16 bf16x2;
typedef __attribute__((ext_vector_type(4))) float  f32x4;

static __device__ __forceinline__ f32x4 ld4(const float* p)  { return *(const f32x4*)p; }
static __device__ __forceinline__ f32x4 ld4(const __bf16* p) {
    bf16x4 v = *(const bf16x4*)p;
    return (f32x4){(float)v[0], (float)v[1], (float)v[2], (float)v[3]};
}
static __device__ __forceinline__ f32x4 ld4_nt(const float* p) {
    return __builtin_nontemporal_load((const f32x4*)p);
}
static __device__ __forceinline__ f32x4 relu4(f32x4 a) {
    return (f32x4){fmaxf(a[0], 0.f), fmaxf(a[1], 0.f), fmaxf(a[2], 0.f), fmaxf(a[3], 0.f)};
}
static __device__ __forceinline__ bf16x4 tobf4(f32x4 a) {
    bf16x4 o; o[0] = (__bf16)a[0]; o[1] = (__bf16)a[1]; o[2] = (__bf16)a[2]; o[3] = (__bf16)a[3];
    return o;
}

// ---------------- prep: zero cnt/flags + weights->bf16 + nfeats->bf16 ----------------
__global__ __launch_bounds__(256) void k_prep(int* __restrict__ cnt, int* __restrict__ flags,
                                              const float* __restrict__ a, __bf16* __restrict__ oa,
                                              const float* __restrict__ b, __bf16* __restrict__ ob,
                                              const float* __restrict__ c, __bf16* __restrict__ oc,
                                              const float* __restrict__ d, __bf16* __restrict__ od,
                                              const float* __restrict__ nf, __bf16* __restrict__ nfbf) {
    int i = blockIdx.x * 256 + threadIdx.x;       // grid 2048 -> 524288 threads
    if (i < 2) flags[i] = 0;
    if (i < NN) cnt[i] = 0;
    if (i < 128 * 384) { oa[i] = (__bf16)a[i]; oc[i] = (__bf16)c[i]; }
    if (i < 128 * 256) { ob[i] = (__bf16)b[i]; od[i] = (__bf16)d[i]; }
    int stride = gridDim.x * 256;
    for (int j = i; j < NN * 128 / 8; j += stride) {
        f32x4 x = __builtin_nontemporal_load((const f32x4*)(nf + (size_t)j * 8));
        f32x4 y = __builtin_nontemporal_load((const f32x4*)(nf + (size_t)j * 8 + 4));
        bf16x8 o;
        o[0] = (__bf16)x[0]; o[1] = (__bf16)x[1]; o[2] = (__bf16)x[2]; o[3] = (__bf16)x[3];
        o[4] = (__bf16)y[0]; o[5] = (__bf16)y[1]; o[6] = (__bf16)y[2]; o[7] = (__bf16)y[3];
        *(bf16x8*)(nfbf + (size_t)j * 8) = o;
    }
}

// ---------------- CSR build ----------------
__global__ __launch_bounds__(256) void k_count(const int* __restrict__ v, int* __restrict__ cnt) {
    int i = blockIdx.x * 256 + threadIdx.x;
    int stride = gridDim.x * 256;
    for (; i < NE; i += stride) {
        int vv = __builtin_nontemporal_load(v + i);
        atomicAdd(&cnt[vv], 1);
    }
}

__global__ __launch_bounds__(1024) void k_scanA(const int* __restrict__ cnt,
                                                int* __restrict__ bsum,
                                                int* __restrict__ boff,
                                                int* __restrict__ off,
                                                int* __restrict__ done) {
    __shared__ int sh[1024];
    int b = blockIdx.x;                 // 0..48
    int t = threadIdx.x;
    int idx = b * 1024 + t;
    int val = (idx < NN) ? cnt[idx] : 0;
    sh[t] = val;
    __syncthreads();
    for (int d = 512; d > 0; d >>= 1) {
        if (t < d) sh[t] += sh[t + d];
        __syncthreads();
    }
    __shared__ int amLast;
    if (t == 0) {
        bsum[b] = sh[0];
        __threadfence();
        amLast = (atomicAdd(done, 1) == 48);
    }
    __syncthreads();
    if (amLast && t < 64) {
        __threadfence();
        int lane = t;
        int s = (lane < 49) ? bsum[lane] : 0;
        int incl = s;
        for (int d = 1; d < 64; d <<= 1) {
            int x = __shfl_up(incl, d);
            if (lane >= d) incl += x;
        }
        if (lane < 49) boff[lane] = incl - s;
        if (lane == 48) off[NN] = incl;
    }
}

__global__ __launch_bounds__(1024) void k_scanC(const int* __restrict__ cnt,
                                                const int* __restrict__ boff,
                                                int* __restrict__ off,
                                                int* __restrict__ cur) {
    __shared__ int sh[1024];
    int b = blockIdx.x;
    int t = threadIdx.x;
    int idx = b * 1024 + t;
    int val = (idx < NN) ? cnt[idx] : 0;
    sh[t] = val;
    __syncthreads();
    for (int d = 1; d < 1024; d <<= 1) {
        int x = (t >= d) ? sh[t - d] : 0;
        __syncthreads();
        sh[t] += x;
        __syncthreads();
    }
    int excl = sh[t] - val + boff[b];
    if (idx < NN) { off[idx] = excl; cur[idx] = excl; }
}

__global__ __launch_bounds__(256) void k_fill(const int* __restrict__ u,
                                              const int* __restrict__ v,
                                              int* __restrict__ cur,
                                              int2* __restrict__ se) {
    int i = blockIdx.x * 256 + threadIdx.x;
    int stride = gridDim.x * 256;
    for (; i < NE; i += stride) {
        int uu = __builtin_nontemporal_load(u + i);
        int vv = __builtin_nontemporal_load(v + i);
        int pos = atomicAdd(&cur[vv], 1);
        se[pos] = make_int2(uu, i);
    }
}

// ============== fused: aggregate 16 nodes -> LDS, node-MLP, P/Q projection ==============
// MODE 0 (layer 1): Ssrc=nfbf[NN,128] (gather+self); ef = efeats f32 (nt stream);
//                   out: h,P -> HP interleaved, Q+be -> Q1out
// MODE 1 (layer 2): Ssrc=HP1[NN,256] (gather h|P rows + self h); Qin = Q1 (pre-biased);
//                   out: h -> Hf f32 (nt, final), P -> P2, Q+be -> Q2
template <int MODE>
__global__ __launch_bounds__(256) void k_agg_mlp(const __bf16* __restrict__ Ssrc,
                                                 const float* __restrict__ ef,
                                                 const __bf16* __restrict__ Qin,
                                                 const int2* __restrict__ se,
                                                 const int* __restrict__ off,
                                                 const __bf16* __restrict__ Wa,
                                                 const float* __restrict__ ba,
                                                 const __bf16* __restrict__ We,
                                                 const float* __restrict__ be,
                                                 __bf16* __restrict__ HP,
                                                 __bf16* __restrict__ Q1out,
                                                 float* __restrict__ Hf,
                                                 __bf16* __restrict__ P2,
                                                 __bf16* __restrict__ Q2) {
    const int K = 384;
    const int SS = (MODE == 0) ? 128 : 256;
    const int wave = threadIdx.x >> 6;
    const int lane = threadIdx.x & 63;
    const int nb = blockIdx.x * 16;               // NN = 3125*16 exactly

    __shared__ __bf16 xlds[16][264];              // means: [.,0:128)=nbr, [.,128:256)=edge; 264 -> 2-way banks
    __shared__ __bf16 hlds[16][136];              // h tile for P/Q GEMM

    // ---- phase 1: each wave aggregates 4 nodes (lanes 0-31 nbr-half, 32-63 edge-half) ----
    {
        const bool isE = lane >= 32;
        const int l = lane & 31;
#pragma unroll
        for (int nd = 0; nd < 4; ++nd) {
            const int row = wave * 4 + nd;
            const int n = nb + row;
            const int p0 = __builtin_amdgcn_readfirstlane(off[n]);
            const int p1 = __builtin_amdgcn_readfirstlane(off[n + 1]);

            f32x4 qb;
            if (MODE == 1) qb = ld4(Qin + (size_t)n * 128 + l * 4);

            f32x4 acc = {0.f, 0.f, 0.f, 0.f};
            int p = p0;
            for (; p + 8 <= p1; p += 8) {
                int2 g[8];
#pragma unroll
                for (int j = 0; j < 8; ++j) g[j] = se[p + j];
                f32x4 t[8];
                if (MODE == 0) {
                    if (isE) {
#pragma unroll
                        for (int j = 0; j < 8; ++j) t[j] = ld4_nt(ef + (size_t)g[j].y * 128 + l * 4);
                    } else {
#pragma unroll
                        for (int j = 0; j < 8; ++j) t[j] = ld4(Ssrc + (size_t)g[j].x * 128 + l * 4);
                    }
#pragma unroll
                    for (int j = 0; j < 8; ++j) acc += t[j];
                } else {
#pragma unroll
                    for (int j = 0; j < 8; ++j) t[j] = ld4(Ssrc + (size_t)g[j].x * 256 + lane * 4);
#pragma unroll
                    for (int j = 0; j < 8; ++j) acc += isE ? relu4(t[j] + qb) : t[j];
                }
            }
            for (; p < p1; ++p) {
                int2 g = se[p];
                if (MODE == 0) {
                    acc += isE ? ld4_nt(ef + (size_t)g.y * 128 + l * 4)
                               : ld4(Ssrc + (size_t)g.x * 128 + l * 4);
                } else {
                    f32x4 t = ld4(Ssrc + (size_t)g.x * 256 + lane * 4);
                    acc += isE ? relu4(t + qb) : t;
                }
            }

            float inv = (p1 > p0) ? 1.f / (float)(p1 - p0) : 0.f;
            f32x4 m = {acc[0] * inv, acc[1] * inv, acc[2] * inv, acc[3] * inv};
            *(bf16x4*)(&xlds[row][(isE ? 128 : 0) + l * 4]) = tobf4(m);
        }
    }
    __syncthreads();

    // ---- phase 2: node MLP, wave owns channel j-pair {2w, 2w+1} for all 16 rows ----
    const int lr = lane & 15;
    const int kg = lane >> 4;
    const int j0 = wave * 2;
    const int node = nb + lr;

    f32x4 acc[2];
    acc[0] = (f32x4){0, 0, 0, 0}; acc[1] = (f32x4){0, 0, 0, 0};

    const __bf16* ps = Ssrc + (size_t)node * SS + 8 * kg;       // self features (k 0-127)
    const __bf16* pwa = Wa + (size_t)lr * K + 8 * kg;

#pragma unroll
    for (int k0 = 0; k0 < 128; k0 += 32) {
        bf16x8 x0 = *(const bf16x8*)(ps + k0);
#pragma unroll
        for (int jj = 0; jj < 2; ++jj) {
            bf16x8 w = *(const bf16x8*)(pwa + (size_t)(j0 + jj) * 16 * K + k0);
            acc[jj] = __builtin_amdgcn_mfma_f32_16x16x32_bf16(w, x0, acc[jj], 0, 0, 0);
        }
    }
#pragma unroll
    for (int k0 = 0; k0 < 256; k0 += 32) {
        bf16x8 x0 = *(const bf16x8*)(&xlds[lr][k0 + 8 * kg]);
#pragma unroll
        for (int jj = 0; jj < 2; ++jj) {
            bf16x8 w = *(const bf16x8*)(pwa + (size_t)(j0 + jj) * 16 * K + 128 + k0);
            acc[jj] = __builtin_amdgcn_mfma_f32_16x16x32_bf16(w, x0, acc[jj], 0, 0, 0);
        }
    }

#pragma unroll
    for (int jj = 0; jj < 2; ++jj) {
        int ch0 = (j0 + jj) * 16 + kg * 4;
        f32x4 bb = *(const f32x4*)(ba + ch0);
        f32x4 val = relu4(acc[jj] + bb);
        bf16x4 vb = tobf4(val);
        *(bf16x4*)(&hlds[lr][ch0]) = vb;
        if (MODE == 0) *(bf16x4*)(HP + (size_t)node * 256 + ch0) = vb;
        else __builtin_nontemporal_store(val, (f32x4*)(Hf + (size_t)node * 128 + ch0));
    }
    __syncthreads();

    // ---- phase 3: P/Q GEMM from LDS h-tile; wave owns j-pair for P and Q ----
    f32x4 accP[2], accQ[2];
    accP[0] = (f32x4){0,0,0,0}; accP[1] = (f32x4){0,0,0,0};
    accQ[0] = (f32x4){0,0,0,0}; accQ[1] = (f32x4){0,0,0,0};

    const __bf16* pwe = We + (size_t)lr * 256 + 8 * kg;
#pragma unroll
    for (int k0 = 0; k0 < 128; k0 += 32) {
        bf16x8 h0 = *(const bf16x8*)(&hlds[lr][k0 + 8 * kg]);
#pragma unroll
        for (int jj = 0; jj < 2; ++jj) {
            bf16x8 wp = *(const bf16x8*)(pwe + (size_t)(j0 + jj) * 16 * 256 + k0);
            bf16x8 wq = *(const bf16x8*)(pwe + (size_t)(j0 + jj) * 16 * 256 + 128 + k0);
            accP[jj] = __builtin_amdgcn_mfma_f32_16x16x32_bf16(wp, h0, accP[jj], 0, 0, 0);
            accQ[jj] = __builtin_amdgcn_mfma_f32_16x16x32_bf16(wq, h0, accQ[jj], 0, 0, 0);
        }
    }

#pragma unroll
    for (int jj = 0; jj < 2; ++jj) {
        int ch0 = (j0 + jj) * 16 + kg * 4;
        f32x4 bq = *(const f32x4*)(be + ch0);         // fold edge-bias into Q
        if (MODE == 0) {
            *(bf16x4*)(HP + (size_t)node * 256 + 128 + ch0) = tobf4(accP[jj]);
            *(bf16x4*)(Q1out + (size_t)node * 128 + ch0)    = tobf4(accQ[jj] + bq);
        } else {
            *(bf16x4*)(P2 + (size_t)node * 128 + ch0) = tobf4(accP[jj]);
            *(bf16x4*)(Q2 + (size_t)node * 128 + ch0) = tobf4(accQ[jj] + bq);
        }
    }
}

// ---------------- final edge op, CSR order (se must NOT alias e2 region!) ----------------
__global__ __launch_bounds__(256) void k_add2_csr(const __bf16* __restrict__ P,
                                                  const __bf16* __restrict__ Q,
                                                  const int2* __restrict__ se,
                                                  const int* __restrict__ off,
                                                  float* __restrict__ out) {
    const int wid  = threadIdx.x >> 6;
    const int lane = threadIdx.x & 63;
    const int n = blockIdx.x * 4 + wid;
    const int p0 = __builtin_amdgcn_readfirstlane(off[n]);
    const int p1 = __builtin_amdgcn_readfirstlane(off[n + 1]);
    const int half = lane >> 5;
    const int l = lane & 31;

    f32x4 qb = ld4(Q + (size_t)n * 128 + l * 4);  // pre-biased, wave-uniform node

    int p = p0 + half;
    for (; p + 6 < p1; p += 8) {                  // 4 edges per half-wave per iter
        int2 g[4];
#pragma unroll
        for (int j = 0; j < 4; ++j) g[j] = se[p + 2 * j];
        f32x4 pv[4];
#pragma unroll
        for (int j = 0; j < 4; ++j) pv[j] = ld4(P + (size_t)g[j].x * 128 + l * 4);
#pragma unroll
        for (int j = 0; j < 4; ++j) {
            f32x4 r = relu4(pv[j] + qb);
            __builtin_nontemporal_store(r, (f32x4*)(out + (size_t)g[j].y * 128 + l * 4));
        }
    }
    for (; p < p1; p += 2) {
        int2 g = se[p];
        f32x4 pv = ld4(P + (size_t)g.x * 128 + l * 4);
        f32x4 r = relu4(pv + qb);
        __builtin_nontemporal_store(r, (f32x4*)(out + (size_t)g.y * 128 + l * 4));
    }
}

// fallback (R8-proven): sequential edge order, reads u/v, no se dependency
__global__ __launch_bounds__(256) void k_add2_seq(const __bf16* __restrict__ P,
                                                  const __bf16* __restrict__ Q,
                                                  const int* __restrict__ u,
                                                  const int* __restrict__ v,
                                                  float* __restrict__ out) {
    const int half = threadIdx.x >> 5;
    const int l = threadIdx.x & 31;
    const int e0 = blockIdx.x * 64 + half * 8;

    int uu[8], vv[8];
#pragma unroll
    for (int j = 0; j < 8; ++j) {
        uu[j] = __builtin_nontemporal_load(u + e0 + j);
        vv[j] = __builtin_nontemporal_load(v + e0 + j);
    }
    f32x4 pv[8], qv[8];
#pragma unroll
    for (int j = 0; j < 8; ++j) {
        pv[j] = ld4(P + (size_t)uu[j] * 128 + l * 4);
        qv[j] = ld4(Q + (size_t)vv[j] * 128 + l * 4);
    }
#pragma unroll
    for (int j = 0; j < 8; ++j) {
        f32x4 r = relu4(pv[j] + qv[j]);
        __builtin_nontemporal_store(r, (f32x4*)(out + (size_t)(e0 + j) * 128 + l * 4));
    }
}

extern "C" void kernel_launch(void* const* d_in, const int* in_sizes, int n_in,
                              void* d_out, int out_size, void* d_ws, size_t ws_size,
                              hipStream_t stream) {
    const float* nfeats = (const float*)d_in[0];
    const float* efeats = (const float*)d_in[1];
    const int*   u      = (const int*)d_in[2];
    const int*   v      = (const int*)d_in[3];
    const float* W1a = (const float*)d_in[4];
    const float* b1a = (const float*)d_in[5];
    const float* W1e = (const float*)d_in[6];
    const float* b1e = (const float*)d_in[7];
    const float* W2a = (const float*)d_in[8];
    const float* b2a = (const float*)d_in[9];
    const float* W2e = (const float*)d_in[10];
    const float* b2e = (const float*)d_in[11];

    float* h2f = (float*)d_out;                       // [NN,128] f32 (output 0)
    float* e2f = h2f + (size_t)NN * 128;              // [NE,128] f32 (output 1)

    // e2-region scratch: ALL dead before the final add2 runs (invariant!)
    char* eb = (char*)e2f;
    __bf16* HP1  = (__bf16*)(eb);                     // [NN,256]  25,600,000 B (h1|P1)
    __bf16* Q1   = (__bf16*)(eb + 25600000);          // [NN,128]  12,800,000 B
    __bf16* nfbf = (__bf16*)(eb + 38400000);          // [NN,128]  12,800,000 B

    char* w = (char*)d_ws;
    int* cnt   = (int*)(w);                  // 200,000 B
    int* off   = (int*)(w + 200000);         // 200,004 B (padded)
    int* cur   = (int*)(w + 400016);         // 200,000 B
    int* bsum  = (int*)(w + 600016);         // 196 B (pad 256)
    int* boff  = (int*)(w + 600272);         // 196 B (pad 256)
    int* flags = (int*)(w + 600528);         // 8 B (pad 16)
    __bf16* w1a = (__bf16*)(w + 600544);     // 98,304 B
    __bf16* w1e = (__bf16*)(w + 698848);     // 65,536 B
    __bf16* w2a = (__bf16*)(w + 764384);     // 98,304 B
    __bf16* w2e = (__bf16*)(w + 862688);     // 65,536 B
    __bf16* P2  = (__bf16*)(w + 928224);     // 12,800,000 B
    __bf16* Q2  = (__bf16*)(w + 13728224);   // 12,800,000 B
    int2*  seWS = (int2*) (w + 26528224);    //  6,400,000 B -> total 32,928,224 B

    bool csr_add = ws_size >= (size_t)32928224;
    int2* se = csr_add ? seWS : (int2*)(eb + 51200000);

    // prep + CSR build
    k_prep<<<2048, 256, 0, stream>>>(cnt, flags, W1a, w1a, W1e, w1e, W2a, w2a, W2e, w2e, nfeats, nfbf);
    k_count<<<1024, 256, 0, stream>>>(v, cnt);
    k_scanA<<<49, 1024, 0, stream>>>(cnt, bsum, boff, off, flags);
    k_scanC<<<49, 1024, 0, stream>>>(cnt, boff, off, cur);
    k_fill<<<1024, 256, 0, stream>>>(u, v, cur, se);

    // layer 1: aggregate + node-MLP + P/Q in one kernel
    k_agg_mlp<0><<<NN / 16, 256, 0, stream>>>(nfbf, efeats, nullptr, se, off,
                                              w1a, b1a, w1e, b1e, HP1, Q1, nullptr, nullptr, nullptr);

    // layer 2: aggregate (fused layer-1 edge-MLP) + node-MLP + P/Q
    k_agg_mlp<1><<<NN / 16, 256, 0, stream>>>(HP1, nullptr, Q1, se, off,
                                              w2a, b2a, w2e, b2e, nullptr, nullptr, h2f, P2, Q2);

    // final edge op
    if (csr_add) k_add2_csr<<<NN / 4, 256, 0, stream>>>(P2, Q2, se, off, e2f);
    else         k_add2_seq<<<NE / 64, 256, 0, stream>>>(P2, Q2, u, v, e2f);
}